// Round 4
// baseline (300.915 us; speedup 1.0000x reference)
//
#include <hip/hip_runtime.h>
#include <math.h>

typedef float f4 __attribute__((ext_vector_type(4)));
typedef float f32x4 __attribute__((ext_vector_type(4)));
typedef _Float16 h4 __attribute__((ext_vector_type(4)));
typedef _Float16 h8 __attribute__((ext_vector_type(8)));

#define BH 32
#define NN 4096
#define DD 64
#define FF 256
#define EE 64
#define SPLITS 16
#define ROWS_K 256
#define QB 16
#define ROWS_Q 256

#define MFMA(a, b, c) __builtin_amdgcn_mfma_f32_16x16x32_f16((a), (b), (c), 0, 0, 0)

__device__ inline h8 cvt2(f4 x0, f4 x1) {
  h8 r;
  r[0] = (_Float16)x0.x; r[1] = (_Float16)x0.y;
  r[2] = (_Float16)x0.z; r[3] = (_Float16)x0.w;
  r[4] = (_Float16)x1.x; r[5] = (_Float16)x1.y;
  r[6] = (_Float16)x1.z; r[7] = (_Float16)x1.w;
  return r;
}

// ---------------------------------------------------------------------------
// prep: PT[f][d] f16 = P[d][f] f32.  4096 threads, one h4 each.
// ---------------------------------------------------------------------------
__global__ __launch_bounds__(512) void fa_prep(const float* __restrict__ P,
                                               _Float16* __restrict__ PT) {
  const int e = blockIdx.x * 512 + threadIdx.x;  // 0..4095
  const int f = e & 255, dq = e >> 8;            // dq 0..15
  h4 o;
#pragma unroll
  for (int j = 0; j < 4; ++j) o[j] = (_Float16)P[(dq * 4 + j) * FF + f];
  *(h4*)&PT[f * DD + dq * 4] = o;
}

// ---------------------------------------------------------------------------
// kside: 512 blocks (bh,split), 512 thr, LB(512,4) -> <=128 VGPR.
// LDS = kpt 64K + vt 16K = exactly 80 KB (XOR-swizzled, pad-free) -> 2 blk/CU.
// Proj B-frags read directly from global PT (L2). ksum via MFMA vs ones-B.
// ---------------------------------------------------------------------------
__global__ __launch_bounds__(512, 4) void fa_kside(
    const float* __restrict__ kin, const float* __restrict__ vin,
    const _Float16* __restrict__ PT, float* __restrict__ kv_part,
    float* __restrict__ ksum_part) {
  __shared__ _Float16 kpt[FF * 128];  // swizzled [f][row]
  __shared__ _Float16 vt[EE * 128];   // swizzled [e][row]

  const int t = threadIdx.x;
  const int w = t >> 6, lane = t & 63;
  const int g = lane >> 4, fl = lane & 15;
  const int bh = blockIdx.x >> 4, split = blockIdx.x & 15;
  const int bhs = blockIdx.x;
  const int k0 = g * 8;
  const int key = fl & 7;

  f32x4 kvacc[2][4];
#pragma unroll
  for (int mi = 0; mi < 2; ++mi)
#pragma unroll
    for (int nt = 0; nt < 4; ++nt) kvacc[mi][nt] = (f32x4){0.f, 0.f, 0.f, 0.f};
  f32x4 ksacc[2];
  ksacc[0] = (f32x4){0.f, 0.f, 0.f, 0.f};
  ksacc[1] = (f32x4){0.f, 0.f, 0.f, 0.f};
  h8 ones;
#pragma unroll
  for (int j = 0; j < 8; ++j) ones[j] = (_Float16)1.0f;

  const size_t base = (size_t)bh * NN * DD + (size_t)split * ROWS_K * DD;

  for (int tile = 0; tile < 2; ++tile) {
    if (tile) __syncthreads();  // WAR vs previous GEMM reads
    const int r0g = tile * 128 + w * 16;

    // ---- stage v^T (released regs before proj) ----
    {
      const float* vb = vin + base + (size_t)r0g * DD + lane;
      h8 tv0, tv1;
#pragma unroll
      for (int j = 0; j < 8; ++j) tv0[j] = (_Float16)vb[j * DD];
#pragma unroll
      for (int j = 0; j < 8; ++j) tv1[j] = (_Float16)vb[(8 + j) * DD];
      *(h8*)&vt[lane * 128 + (((w * 2 + 0) ^ (lane & 7)) << 3)] = tv0;
      *(h8*)&vt[lane * 128 + (((w * 2 + 1) ^ (lane & 7)) << 3)] = tv1;
    }

    // ---- k A-frags from global ----
    const float* krow = kin + base + (size_t)(r0g + fl) * DD;
    h8 a0 = cvt2(*(const f4*)&krow[k0], *(const f4*)&krow[k0 + 4]);
    h8 a1 = cvt2(*(const f4*)&krow[32 + k0], *(const f4*)&krow[36 + k0]);

    // ---- projection (B-frags from global PT, L2-resident) ----
    f32x4 lac[16];
#pragma unroll
    for (int T = 0; T < 16; ++T) {
      const int ncol = T * 16 + fl;
      h8 b0 = *(const h8*)&PT[ncol * DD + k0];
      h8 b1 = *(const h8*)&PT[ncol * DD + 32 + k0];
      f32x4 c = {0.f, 0.f, 0.f, 0.f};
      c = MFMA(a0, b0, c);
      c = MFMA(a1, b1, c);
      lac[T] = c;
    }

    // ---- in-wave rowmax ----
    float mrow[4];
#pragma unroll
    for (int rg = 0; rg < 4; ++rg) {
      float m = lac[0][rg];
#pragma unroll
      for (int T = 1; T < 16; ++T) m = fmaxf(m, lac[T][rg]);
#pragma unroll
      for (int off = 1; off <= 8; off <<= 1)
        m = fmaxf(m, __shfl_xor(m, off, 64));
      mrow[rg] = m;
    }

    // ---- exp + swizzled kp^T write ----
#pragma unroll
    for (int T = 0; T < 16; ++T) {
      const int ncol = T * 16 + fl;
      h4 kp;
#pragma unroll
      for (int rg = 0; rg < 4; ++rg)
        kp[rg] = (_Float16)(__expf(lac[T][rg] - mrow[rg]) * 0.0625f);
      *(h4*)&kpt[ncol * 128 + (((w * 2 + (g >> 1)) ^ key) << 3) + (g & 1) * 4] =
          kp;
    }
    __syncthreads();  // kpt + vt ready

    // ---- kv GEMM + ksum (ones-B) ----
#pragma unroll
    for (int kst = 0; kst < 4; ++kst) {
      h8 vbf[4];
#pragma unroll
      for (int nt = 0; nt < 4; ++nt)
        vbf[nt] =
            *(const h8*)&vt[(nt * 16 + fl) * 128 + (((kst * 4 + g) ^ key) << 3)];
#pragma unroll
      for (int mi = 0; mi < 2; ++mi) {
        h8 ka = *(const h8*)&kpt[((2 * w + mi) * 16 + fl) * 128 +
                                 (((kst * 4 + g) ^ key) << 3)];
#pragma unroll
        for (int nt = 0; nt < 4; ++nt)
          kvacc[mi][nt] = MFMA(ka, vbf[nt], kvacc[mi][nt]);
        ksacc[mi] = MFMA(ka, ones, ksacc[mi]);
      }
    }
  }

  // ---- write partials ----
  float* kvp = kv_part + (size_t)bhs * (FF * EE);
#pragma unroll
  for (int mi = 0; mi < 2; ++mi)
#pragma unroll
    for (int nt = 0; nt < 4; ++nt)
#pragma unroll
      for (int rg = 0; rg < 4; ++rg)
        kvp[((2 * w + mi) * 16 + g * 4 + rg) * EE + nt * 16 + fl] =
            kvacc[mi][nt][rg];
  if (fl == 0) {
#pragma unroll
    for (int mi = 0; mi < 2; ++mi)
#pragma unroll
      for (int rg = 0; rg < 4; ++rg)
        ksum_part[(size_t)bhs * FF + (2 * w + mi) * 16 + g * 4 + rg] =
            ksacc[mi][rg];
  }
}

// ---------------------------------------------------------------------------
// reduce: 512 blocks kv (bh x 16-f-slice) + 32 blocks ksum.
// ---------------------------------------------------------------------------
__global__ __launch_bounds__(256) void fa_reduce(
    const float* __restrict__ kv_part, const float* __restrict__ ksum_part,
    _Float16* __restrict__ kvt_g, float* __restrict__ ksum_g) {
  __shared__ _Float16 tl[EE * 18];
  const int b = blockIdx.x, t = threadIdx.x;
  if (b < 512) {
    const int bh = b >> 4, c = b & 15;
#pragma unroll
    for (int i = 0; i < 4; ++i) {
      int idx = i * 256 + t;
      int fr = idx >> 6, e = idx & 63;
      float s = 0.f;
#pragma unroll
      for (int sp = 0; sp < SPLITS; ++sp)
        s += kv_part[(size_t)(bh * SPLITS + sp) * (FF * EE) +
                     (c * 16 + fr) * EE + e];
      tl[e * 18 + fr] = (_Float16)s;
    }
    __syncthreads();
    unsigned int* og = (unsigned int*)kvt_g + (size_t)bh * 8192;
#pragma unroll
    for (int i = 0; i < 2; ++i) {
      int idx = i * 256 + t;
      int e = idx >> 3, j = idx & 7;
      og[e * 128 + c * 8 + j] = *(unsigned int*)&tl[e * 18 + j * 2];
    }
  } else {
    const int bh = b - 512;
    float s = 0.f;
#pragma unroll
    for (int sp = 0; sp < SPLITS; ++sp)
      s += ksum_part[(size_t)(bh * SPLITS + sp) * FF + t];
    ksum_g[bh * FF + t] = s + 1e-6f;
  }
}

// ---------------------------------------------------------------------------
// qside: 512 blocks (bh,qb), 512 thr, LB(512,4). LDS = PT 32K + kvt 32K +
// qpt 16K = exactly 80 KB -> 2 blk/CU. Zero inner barriers; 4-pass
// quarter-slice qp staging (wave-private); denom via per-T ksum reload (L1).
// ---------------------------------------------------------------------------
__global__ __launch_bounds__(512, 4) void fa_qside(
    const float* __restrict__ qin, const _Float16* __restrict__ PTg,
    const _Float16* __restrict__ kvt_g, const float* __restrict__ ksum_g,
    float* __restrict__ out) {
  __shared__ _Float16 PTl[FF * DD];      // swizzled [f][d]   32 KB
  __shared__ _Float16 kvt[EE * FF];      // swizzled [e][f]   32 KB
  __shared__ _Float16 qpt[8 * 16 * 64];  // wave-private [r][f-quarter] 16 KB

  const int t = threadIdx.x;
  const int w = t >> 6, lane = t & 63;
  const int g = lane >> 4, fl = lane & 15;
  const int bh = blockIdx.x >> 4, qb = blockIdx.x & 15;
  const int k0 = g * 8;
  const int key = fl & 7;

  {  // stage PT (swizzled)
    const h8* src = (const h8*)PTg;  // 2048 h8
#pragma unroll
    for (int i = 0; i < 4; ++i) {
      int idx = t + i * 512;
      int f = idx >> 3, c0 = idx & 7;
      *(h8*)&PTl[f * DD + ((c0 ^ (f & 7)) << 3)] = src[idx];
    }
  }
  {  // stage kv^T (swizzled)
    const h8* src = (const h8*)(kvt_g + (size_t)bh * FF * EE);
#pragma unroll
    for (int i = 0; i < 4; ++i) {
      int idx = t + i * 512;
      int e = idx >> 5, c0 = idx & 31;
      *(h8*)&kvt[e * FF + ((c0 ^ (e & 7)) << 3)] = src[idx];
    }
  }
  __syncthreads();  // the only barrier

  _Float16* myqpt = qpt + w * 1024;
  const float* ksb = ksum_g + bh * FF;
  const size_t base = (size_t)bh * NN * DD + (size_t)qb * ROWS_Q * DD;
  float* ob = out + (size_t)bh * NN * EE + (size_t)qb * ROWS_Q * EE;

  for (int st = 0; st < 2; ++st) {
    const int r0g = st * 128 + w * 16;
    const float* qrow = qin + base + (size_t)(r0g + fl) * DD;
    h8 a0 = cvt2(*(const f4*)&qrow[k0], *(const f4*)&qrow[k0 + 4]);
    h8 a1 = cvt2(*(const f4*)&qrow[32 + k0], *(const f4*)&qrow[36 + k0]);

    f32x4 lac[16];
#pragma unroll
    for (int T = 0; T < 16; ++T) {
      const int ncol = T * 16 + fl;
      h8 b0 = *(const h8*)&PTl[ncol * DD + (((0 * 4 + g) ^ key) << 3)];
      h8 b1 = *(const h8*)&PTl[ncol * DD + (((1 * 4 + g) ^ key) << 3)];
      f32x4 c = {0.f, 0.f, 0.f, 0.f};
      c = MFMA(a0, b0, c);
      c = MFMA(a1, b1, c);
      lac[T] = c;
    }

    float mrow[4];
#pragma unroll
    for (int rg = 0; rg < 4; ++rg) {
      float m = lac[0][rg];
#pragma unroll
      for (int T = 1; T < 16; ++T) m = fmaxf(m, lac[T][rg]);
#pragma unroll
      for (int off = 1; off <= 8; off <<= 1)
        m = fmaxf(m, __shfl_xor(m, off, 64));
      mrow[rg] = m;
    }

    float den[4] = {0.f, 0.f, 0.f, 0.f};
    f32x4 oacc[4];
#pragma unroll
    for (int nt = 0; nt < 4; ++nt) oacc[nt] = (f32x4){0.f, 0.f, 0.f, 0.f};

    // 4 passes: exp quarter -> wave-private qpt -> 2 kst GEMM steps
#pragma unroll
    for (int p = 0; p < 4; ++p) {
#pragma unroll
      for (int tt = 0; tt < 4; ++tt) {
        const int T = p * 4 + tt;
        const float ks = ksb[T * 16 + fl];
#pragma unroll
        for (int rg = 0; rg < 4; ++rg) {
          float ev = __expf(lac[T][rg] - mrow[rg]) * 0.0625f;
          _Float16 hv = (_Float16)ev;
          den[rg] += (float)hv * ks;
          const int r = g * 4 + rg;
          myqpt[r * 64 + (((tt * 2 + (fl >> 3)) ^ (r & 7)) << 3) + (fl & 7)] =
              hv;
        }
      }
#pragma unroll
      for (int k2 = 0; k2 < 2; ++k2) {
        const int kst = p * 2 + k2;
        h8 aq = *(const h8*)&myqpt[fl * 64 + (((k2 * 4 + g) ^ key) << 3)];
#pragma unroll
        for (int nt = 0; nt < 4; ++nt) {
          h8 bq = *(const h8*)&kvt[(nt * 16 + fl) * FF +
                                   (((kst * 4 + g) ^ key) << 3)];
          oacc[nt] = MFMA(aq, bq, oacc[nt]);
        }
      }
    }

#pragma unroll
    for (int rg = 0; rg < 4; ++rg) {
#pragma unroll
      for (int off = 1; off <= 8; off <<= 1)
        den[rg] += __shfl_xor(den[rg], off, 64);
    }

    float* obt = ob + (size_t)r0g * EE;
#pragma unroll
    for (int rg = 0; rg < 4; ++rg) {
      float inv = 1.0f / den[rg];
#pragma unroll
      for (int nt = 0; nt < 4; ++nt)
        obt[(g * 4 + rg) * EE + nt * 16 + fl] = oacc[nt][rg] * inv;
    }
  }
}

extern "C" void kernel_launch(void* const* d_in, const int* in_sizes, int n_in,
                              void* d_out, int out_size, void* d_ws,
                              size_t ws_size, hipStream_t stream) {
  (void)in_sizes;
  (void)n_in;
  (void)out_size;
  (void)ws_size;
  const float* q = (const float*)d_in[0];
  const float* k = (const float*)d_in[1];
  const float* v = (const float*)d_in[2];
  const float* P = (const float*)d_in[3];
  float* out = (float*)d_out;

  float* kv_part = (float*)d_ws;                          // 512*16384 f32
  float* ksum_part = kv_part + (size_t)512 * 16384;       // 512*256 f32
  _Float16* kvt_g = (_Float16*)(ksum_part + 512 * 256);   // 32*16384 f16
  float* ksum_g = (float*)(kvt_g + (size_t)BH * FF * EE); // 32*256 f32
  _Float16* PT = (_Float16*)(ksum_g + BH * FF);           // 256*64 f16

  hipLaunchKernelGGL(fa_prep, dim3(8), dim3(512), 0, stream, P, PT);
  hipLaunchKernelGGL(fa_kside, dim3(BH * SPLITS), dim3(512), 0, stream, k, v,
                     PT, kv_part, ksum_part);
  hipLaunchKernelGGL(fa_reduce, dim3(544), dim3(256), 0, stream, kv_part,
                     ksum_part, kvt_g, ksum_g);
  hipLaunchKernelGGL(fa_qside, dim3(BH * QB), dim3(512), 0, stream, q, PT,
                     kvt_g, ksum_g, out);
}

// Round 5
// 231.694 us; speedup vs baseline: 1.2988x; 1.2988x over previous
//
#include <hip/hip_runtime.h>
#include <math.h>

typedef float f4 __attribute__((ext_vector_type(4)));
typedef float f32x4 __attribute__((ext_vector_type(4)));
typedef _Float16 h4 __attribute__((ext_vector_type(4)));
typedef _Float16 h8 __attribute__((ext_vector_type(8)));

#define BH 32
#define NN 4096
#define DD 64
#define FF 256
#define EE 64
#define SPLITS 16
#define ROWS_K 256
#define QB 16
#define ROWS_Q 256

#define MFMA(a, b, c) __builtin_amdgcn_mfma_f32_16x16x32_f16((a), (b), (c), 0, 0, 0)

__device__ inline h8 cvt2(f4 x0, f4 x1) {
  h8 r;
  r[0] = (_Float16)x0.x; r[1] = (_Float16)x0.y;
  r[2] = (_Float16)x0.z; r[3] = (_Float16)x0.w;
  r[4] = (_Float16)x1.x; r[5] = (_Float16)x1.y;
  r[6] = (_Float16)x1.z; r[7] = (_Float16)x1.w;
  return r;
}

// ---------------------------------------------------------------------------
// prep: PT[f][d] f16 = P[d][f] f32.  4096 threads, one h4 each.
// ---------------------------------------------------------------------------
__global__ __launch_bounds__(512) void fa_prep(const float* __restrict__ P,
                                               _Float16* __restrict__ PT) {
  const int e = blockIdx.x * 512 + threadIdx.x;  // 0..4095
  const int f = e & 255, dq = e >> 8;            // dq 0..15
  h4 o;
#pragma unroll
  for (int j = 0; j < 4; ++j) o[j] = (_Float16)P[(dq * 4 + j) * FF + f];
  *(h4*)&PT[f * DD + dq * 4] = o;
}

// ---------------------------------------------------------------------------
// kside: 512 blocks (bh,split), 512 thr.
// LB(512,2): HIP treats arg2 CUDA-style = min BLOCKS/CU -> VGPR cap 128.
// (LB(512,4) in R4 capped at 64 VGPR -> 160 MB scratch spill each way.)
// LDS = kpt 64K + vt 16K = exactly 80 KB (XOR-swizzled) -> 2 blk/CU resident.
// Proj B-frags read directly from global PT (L2). ksum via MFMA vs ones-B.
// ---------------------------------------------------------------------------
__global__ __launch_bounds__(512, 2) void fa_kside(
    const float* __restrict__ kin, const float* __restrict__ vin,
    const _Float16* __restrict__ PT, float* __restrict__ kv_part,
    float* __restrict__ ksum_part) {
  __shared__ _Float16 kpt[FF * 128];  // swizzled [f][row]
  __shared__ _Float16 vt[EE * 128];   // swizzled [e][row]

  const int t = threadIdx.x;
  const int w = t >> 6, lane = t & 63;
  const int g = lane >> 4, fl = lane & 15;
  const int bh = blockIdx.x >> 4, split = blockIdx.x & 15;
  const int bhs = blockIdx.x;
  const int k0 = g * 8;
  const int key = fl & 7;

  f32x4 kvacc[2][4];
#pragma unroll
  for (int mi = 0; mi < 2; ++mi)
#pragma unroll
    for (int nt = 0; nt < 4; ++nt) kvacc[mi][nt] = (f32x4){0.f, 0.f, 0.f, 0.f};
  f32x4 ksacc[2];
  ksacc[0] = (f32x4){0.f, 0.f, 0.f, 0.f};
  ksacc[1] = (f32x4){0.f, 0.f, 0.f, 0.f};
  h8 ones;
#pragma unroll
  for (int j = 0; j < 8; ++j) ones[j] = (_Float16)1.0f;

  const size_t base = (size_t)bh * NN * DD + (size_t)split * ROWS_K * DD;

  for (int tile = 0; tile < 2; ++tile) {
    if (tile) __syncthreads();  // WAR vs previous GEMM reads
    const int r0g = tile * 128 + w * 16;

    // ---- stage v^T (released regs before proj) ----
    {
      const float* vb = vin + base + (size_t)r0g * DD + lane;
      h8 tv0, tv1;
#pragma unroll
      for (int j = 0; j < 8; ++j) tv0[j] = (_Float16)vb[j * DD];
#pragma unroll
      for (int j = 0; j < 8; ++j) tv1[j] = (_Float16)vb[(8 + j) * DD];
      *(h8*)&vt[lane * 128 + (((w * 2 + 0) ^ (lane & 7)) << 3)] = tv0;
      *(h8*)&vt[lane * 128 + (((w * 2 + 1) ^ (lane & 7)) << 3)] = tv1;
    }

    // ---- k A-frags from global ----
    const float* krow = kin + base + (size_t)(r0g + fl) * DD;
    h8 a0 = cvt2(*(const f4*)&krow[k0], *(const f4*)&krow[k0 + 4]);
    h8 a1 = cvt2(*(const f4*)&krow[32 + k0], *(const f4*)&krow[36 + k0]);

    // ---- projection (B-frags from global PT, L2-resident) ----
    f32x4 lac[16];
#pragma unroll
    for (int T = 0; T < 16; ++T) {
      const int ncol = T * 16 + fl;
      h8 b0 = *(const h8*)&PT[ncol * DD + k0];
      h8 b1 = *(const h8*)&PT[ncol * DD + 32 + k0];
      f32x4 c = {0.f, 0.f, 0.f, 0.f};
      c = MFMA(a0, b0, c);
      c = MFMA(a1, b1, c);
      lac[T] = c;
    }

    // ---- in-wave rowmax ----
    float mrow[4];
#pragma unroll
    for (int rg = 0; rg < 4; ++rg) {
      float m = lac[0][rg];
#pragma unroll
      for (int T = 1; T < 16; ++T) m = fmaxf(m, lac[T][rg]);
#pragma unroll
      for (int off = 1; off <= 8; off <<= 1)
        m = fmaxf(m, __shfl_xor(m, off, 64));
      mrow[rg] = m;
    }

    // ---- exp + swizzled kp^T write ----
#pragma unroll
    for (int T = 0; T < 16; ++T) {
      const int ncol = T * 16 + fl;
      h4 kp;
#pragma unroll
      for (int rg = 0; rg < 4; ++rg)
        kp[rg] = (_Float16)(__expf(lac[T][rg] - mrow[rg]) * 0.0625f);
      *(h4*)&kpt[ncol * 128 + (((w * 2 + (g >> 1)) ^ key) << 3) + (g & 1) * 4] =
          kp;
    }
    __syncthreads();  // kpt + vt ready

    // ---- kv GEMM + ksum (ones-B) ----
#pragma unroll
    for (int kst = 0; kst < 4; ++kst) {
      h8 vbf[4];
#pragma unroll
      for (int nt = 0; nt < 4; ++nt)
        vbf[nt] =
            *(const h8*)&vt[(nt * 16 + fl) * 128 + (((kst * 4 + g) ^ key) << 3)];
#pragma unroll
      for (int mi = 0; mi < 2; ++mi) {
        h8 ka = *(const h8*)&kpt[((2 * w + mi) * 16 + fl) * 128 +
                                 (((kst * 4 + g) ^ key) << 3)];
#pragma unroll
        for (int nt = 0; nt < 4; ++nt)
          kvacc[mi][nt] = MFMA(ka, vbf[nt], kvacc[mi][nt]);
        ksacc[mi] = MFMA(ka, ones, ksacc[mi]);
      }
    }
  }

  // ---- write partials ----
  float* kvp = kv_part + (size_t)bhs * (FF * EE);
#pragma unroll
  for (int mi = 0; mi < 2; ++mi)
#pragma unroll
    for (int nt = 0; nt < 4; ++nt)
#pragma unroll
      for (int rg = 0; rg < 4; ++rg)
        kvp[((2 * w + mi) * 16 + g * 4 + rg) * EE + nt * 16 + fl] =
            kvacc[mi][nt][rg];
  if (fl == 0) {
#pragma unroll
    for (int mi = 0; mi < 2; ++mi)
#pragma unroll
      for (int rg = 0; rg < 4; ++rg)
        ksum_part[(size_t)bhs * FF + (2 * w + mi) * 16 + g * 4 + rg] =
            ksacc[mi][rg];
  }
}

// ---------------------------------------------------------------------------
// reduce: 512 blocks kv (bh x 16-f-slice) + 32 blocks ksum.
// ---------------------------------------------------------------------------
__global__ __launch_bounds__(256) void fa_reduce(
    const float* __restrict__ kv_part, const float* __restrict__ ksum_part,
    _Float16* __restrict__ kvt_g, float* __restrict__ ksum_g) {
  __shared__ _Float16 tl[EE * 18];
  const int b = blockIdx.x, t = threadIdx.x;
  if (b < 512) {
    const int bh = b >> 4, c = b & 15;
#pragma unroll
    for (int i = 0; i < 4; ++i) {
      int idx = i * 256 + t;
      int fr = idx >> 6, e = idx & 63;
      float s = 0.f;
#pragma unroll
      for (int sp = 0; sp < SPLITS; ++sp)
        s += kv_part[(size_t)(bh * SPLITS + sp) * (FF * EE) +
                     (c * 16 + fr) * EE + e];
      tl[e * 18 + fr] = (_Float16)s;
    }
    __syncthreads();
    unsigned int* og = (unsigned int*)kvt_g + (size_t)bh * 8192;
#pragma unroll
    for (int i = 0; i < 2; ++i) {
      int idx = i * 256 + t;
      int e = idx >> 3, j = idx & 7;
      og[e * 128 + c * 8 + j] = *(unsigned int*)&tl[e * 18 + j * 2];
    }
  } else {
    const int bh = b - 512;
    float s = 0.f;
#pragma unroll
    for (int sp = 0; sp < SPLITS; ++sp)
      s += ksum_part[(size_t)(bh * SPLITS + sp) * FF + t];
    ksum_g[bh * FF + t] = s + 1e-6f;
  }
}

// ---------------------------------------------------------------------------
// qside: 512 blocks (bh,qb), 512 thr, LB(512,2) -> VGPR cap 128 (88 needed).
// LDS = PT 32K + kvt 32K + qpt 16K = exactly 80 KB -> 2 blk/CU. Zero inner
// barriers; 4-pass quarter-slice qp staging (wave-private); per-T ksum (L1).
// ---------------------------------------------------------------------------
__global__ __launch_bounds__(512, 2) void fa_qside(
    const float* __restrict__ qin, const _Float16* __restrict__ PTg,
    const _Float16* __restrict__ kvt_g, const float* __restrict__ ksum_g,
    float* __restrict__ out) {
  __shared__ _Float16 PTl[FF * DD];      // swizzled [f][d]   32 KB
  __shared__ _Float16 kvt[EE * FF];      // swizzled [e][f]   32 KB
  __shared__ _Float16 qpt[8 * 16 * 64];  // wave-private [r][f-quarter] 16 KB

  const int t = threadIdx.x;
  const int w = t >> 6, lane = t & 63;
  const int g = lane >> 4, fl = lane & 15;
  const int bh = blockIdx.x >> 4, qb = blockIdx.x & 15;
  const int k0 = g * 8;
  const int key = fl & 7;

  {  // stage PT (swizzled)
    const h8* src = (const h8*)PTg;  // 2048 h8
#pragma unroll
    for (int i = 0; i < 4; ++i) {
      int idx = t + i * 512;
      int f = idx >> 3, c0 = idx & 7;
      *(h8*)&PTl[f * DD + ((c0 ^ (f & 7)) << 3)] = src[idx];
    }
  }
  {  // stage kv^T (swizzled)
    const h8* src = (const h8*)(kvt_g + (size_t)bh * FF * EE);
#pragma unroll
    for (int i = 0; i < 4; ++i) {
      int idx = t + i * 512;
      int e = idx >> 5, c0 = idx & 31;
      *(h8*)&kvt[e * FF + ((c0 ^ (e & 7)) << 3)] = src[idx];
    }
  }
  __syncthreads();  // the only barrier

  _Float16* myqpt = qpt + w * 1024;
  const float* ksb = ksum_g + bh * FF;
  const size_t base = (size_t)bh * NN * DD + (size_t)qb * ROWS_Q * DD;
  float* ob = out + (size_t)bh * NN * EE + (size_t)qb * ROWS_Q * EE;

  for (int st = 0; st < 2; ++st) {
    const int r0g = st * 128 + w * 16;
    const float* qrow = qin + base + (size_t)(r0g + fl) * DD;
    h8 a0 = cvt2(*(const f4*)&qrow[k0], *(const f4*)&qrow[k0 + 4]);
    h8 a1 = cvt2(*(const f4*)&qrow[32 + k0], *(const f4*)&qrow[36 + k0]);

    f32x4 lac[16];
#pragma unroll
    for (int T = 0; T < 16; ++T) {
      const int ncol = T * 16 + fl;
      h8 b0 = *(const h8*)&PTl[ncol * DD + (((0 * 4 + g) ^ key) << 3)];
      h8 b1 = *(const h8*)&PTl[ncol * DD + (((1 * 4 + g) ^ key) << 3)];
      f32x4 c = {0.f, 0.f, 0.f, 0.f};
      c = MFMA(a0, b0, c);
      c = MFMA(a1, b1, c);
      lac[T] = c;
    }

    float mrow[4];
#pragma unroll
    for (int rg = 0; rg < 4; ++rg) {
      float m = lac[0][rg];
#pragma unroll
      for (int T = 1; T < 16; ++T) m = fmaxf(m, lac[T][rg]);
#pragma unroll
      for (int off = 1; off <= 8; off <<= 1)
        m = fmaxf(m, __shfl_xor(m, off, 64));
      mrow[rg] = m;
    }

    float den[4] = {0.f, 0.f, 0.f, 0.f};
    f32x4 oacc[4];
#pragma unroll
    for (int nt = 0; nt < 4; ++nt) oacc[nt] = (f32x4){0.f, 0.f, 0.f, 0.f};

    // 4 passes: exp quarter -> wave-private qpt -> 2 kst GEMM steps
#pragma unroll
    for (int p = 0; p < 4; ++p) {
#pragma unroll
      for (int tt = 0; tt < 4; ++tt) {
        const int T = p * 4 + tt;
        const float ks = ksb[T * 16 + fl];
#pragma unroll
        for (int rg = 0; rg < 4; ++rg) {
          float ev = __expf(lac[T][rg] - mrow[rg]) * 0.0625f;
          _Float16 hv = (_Float16)ev;
          den[rg] += (float)hv * ks;
          const int r = g * 4 + rg;
          myqpt[r * 64 + (((tt * 2 + (fl >> 3)) ^ (r & 7)) << 3) + (fl & 7)] =
              hv;
        }
      }
#pragma unroll
      for (int k2 = 0; k2 < 2; ++k2) {
        const int kst = p * 2 + k2;
        h8 aq = *(const h8*)&myqpt[fl * 64 + (((k2 * 4 + g) ^ key) << 3)];
#pragma unroll
        for (int nt = 0; nt < 4; ++nt) {
          h8 bq = *(const h8*)&kvt[(nt * 16 + fl) * FF +
                                   (((kst * 4 + g) ^ key) << 3)];
          oacc[nt] = MFMA(aq, bq, oacc[nt]);
        }
      }
    }

#pragma unroll
    for (int rg = 0; rg < 4; ++rg) {
#pragma unroll
      for (int off = 1; off <= 8; off <<= 1)
        den[rg] += __shfl_xor(den[rg], off, 64);
    }

    float* obt = ob + (size_t)r0g * EE;
#pragma unroll
    for (int rg = 0; rg < 4; ++rg) {
      float inv = 1.0f / den[rg];
#pragma unroll
      for (int nt = 0; nt < 4; ++nt)
        obt[(g * 4 + rg) * EE + nt * 16 + fl] = oacc[nt][rg] * inv;
    }
  }
}

extern "C" void kernel_launch(void* const* d_in, const int* in_sizes, int n_in,
                              void* d_out, int out_size, void* d_ws,
                              size_t ws_size, hipStream_t stream) {
  (void)in_sizes;
  (void)n_in;
  (void)out_size;
  (void)ws_size;
  const float* q = (const float*)d_in[0];
  const float* k = (const float*)d_in[1];
  const float* v = (const float*)d_in[2];
  const float* P = (const float*)d_in[3];
  float* out = (float*)d_out;

  float* kv_part = (float*)d_ws;                          // 512*16384 f32
  float* ksum_part = kv_part + (size_t)512 * 16384;       // 512*256 f32
  _Float16* kvt_g = (_Float16*)(ksum_part + 512 * 256);   // 32*16384 f16
  float* ksum_g = (float*)(kvt_g + (size_t)BH * FF * EE); // 32*256 f32
  _Float16* PT = (_Float16*)(ksum_g + BH * FF);           // 256*64 f16

  hipLaunchKernelGGL(fa_prep, dim3(8), dim3(512), 0, stream, P, PT);
  hipLaunchKernelGGL(fa_kside, dim3(BH * SPLITS), dim3(512), 0, stream, k, v,
                     PT, kv_part, ksum_part);
  hipLaunchKernelGGL(fa_reduce, dim3(544), dim3(256), 0, stream, kv_part,
                     ksum_part, kvt_g, ksum_g);
  hipLaunchKernelGGL(fa_qside, dim3(BH * QB), dim3(512), 0, stream, q, PT,
                     kvt_g, ksum_g, out);
}